// Round 1
// baseline (108.805 us; speedup 1.0000x reference)
//
#include <hip/hip_runtime.h>
#include <hip/hip_bf16.h>

// B=128, LQ=32, LD=256, HID=768, DIM=128
typedef __attribute__((ext_vector_type(8))) short short8;
typedef __attribute__((ext_vector_type(4))) short short4v;
typedef __attribute__((ext_vector_type(4))) float f32x4;

#define MFMA16(a, b, c) __builtin_amdgcn_mfma_f32_16x16x32_bf16(a, b, c, 0, 0, 0)

__device__ __forceinline__ short f2bf(float f) {
    union { float f; unsigned u; } x; x.f = f;
    unsigned r = x.u + 0x7fffu + ((x.u >> 16) & 1u);  // RNE
    return (short)(r >> 16);
}

// ---------------------------------------------------------------------------
// Kernel 1: P[row][dim] = l2norm( X[row,:768] @ W[dim,:768]^T ), bf16 out.
// MFMA mapping: A = W (M=dim), B = X rows (N=row), K = hid.
// Block: 256 thr = 4 waves, each wave computes 16 rows x 128 dims.
// ---------------------------------------------------------------------------
__global__ __launch_bounds__(256) void proj_norm_kernel(
    const float* __restrict__ qh, const float* __restrict__ dh,
    const float* __restrict__ W, const int* __restrict__ dmask,
    unsigned short* __restrict__ Qb, unsigned short* __restrict__ Db)
{
    __shared__ __align__(16) short Wlds[128][40];  // 32 k-chunk + 8 pad (bank-conflict fix)

    const int tid = threadIdx.x;
    const int wave = tid >> 6, lane = tid & 63;
    const int l = lane & 15, g = lane >> 4;

    const int rowbase = blockIdx.x * 64 + wave * 16;   // 0..36863 (Q rows then D rows)
    const bool isQ = rowbase < 4096;
    const float* X = isQ ? qh : dh;
    unsigned short* P = isQ ? Qb : Db;
    const int prow = isQ ? rowbase : rowbase - 4096;
    const int myrow = prow + l;   // this lane's output row (C col = lane&15)

    f32x4 acc[8];
    #pragma unroll
    for (int m = 0; m < 8; ++m) acc[m] = (f32x4)(0.0f);

    const int wdim = tid >> 1, whalf = tid & 1;  // staging assignment

    for (int k0 = 0; k0 < 768; k0 += 32) {
        // --- stage W[:, k0:k0+32] -> LDS bf16 (each thread: 16 floats) ---
        {
            const float4* s4 = reinterpret_cast<const float4*>(W + wdim * 768 + k0 + whalf * 16);
            float4 w0 = s4[0], w1 = s4[1], w2 = s4[2], w3 = s4[3];
            short8 v0, v1;
            v0[0]=f2bf(w0.x); v0[1]=f2bf(w0.y); v0[2]=f2bf(w0.z); v0[3]=f2bf(w0.w);
            v0[4]=f2bf(w1.x); v0[5]=f2bf(w1.y); v0[6]=f2bf(w1.z); v0[7]=f2bf(w1.w);
            v1[0]=f2bf(w2.x); v1[1]=f2bf(w2.y); v1[2]=f2bf(w2.z); v1[3]=f2bf(w2.w);
            v1[4]=f2bf(w3.x); v1[5]=f2bf(w3.y); v1[6]=f2bf(w3.z); v1[7]=f2bf(w3.w);
            short* dst = &Wlds[wdim][whalf * 16];
            reinterpret_cast<short8*>(dst)[0] = v0;
            reinterpret_cast<short8*>(dst)[1] = v1;
        }
        __syncthreads();

        // --- B fragment: X[myrow][k0 + g*8 + 0..7] fp32 -> bf16 ---
        const float* xp = X + (size_t)myrow * 768 + k0 + g * 8;
        float4 b0 = reinterpret_cast<const float4*>(xp)[0];
        float4 b1 = reinterpret_cast<const float4*>(xp)[1];
        short8 bfrag;
        bfrag[0]=f2bf(b0.x); bfrag[1]=f2bf(b0.y); bfrag[2]=f2bf(b0.z); bfrag[3]=f2bf(b0.w);
        bfrag[4]=f2bf(b1.x); bfrag[5]=f2bf(b1.y); bfrag[6]=f2bf(b1.z); bfrag[7]=f2bf(b1.w);

        // --- A fragments from LDS + 8 MFMAs (dims m*16..m*16+15) ---
        #pragma unroll
        for (int m = 0; m < 8; ++m) {
            short8 afrag = *reinterpret_cast<const short8*>(&Wlds[m * 16 + l][g * 8]);
            acc[m] = MFMA16(afrag, bfrag, acc[m]);
        }
        __syncthreads();
    }

    // --- L2 norm: lane owns row `myrow`; dims covered = m*16 + g*4 + r ---
    float ss = 0.f;
    #pragma unroll
    for (int m = 0; m < 8; ++m)
        #pragma unroll
        for (int r = 0; r < 4; ++r) ss += acc[m][r] * acc[m][r];
    ss += __shfl_xor(ss, 16);
    ss += __shfl_xor(ss, 32);
    float rn = rsqrtf(ss);
    if (!isQ && dmask[myrow] == 0) rn = 0.f;   // zero masked doc tokens

    #pragma unroll
    for (int m = 0; m < 8; ++m) {
        short4v o;
        #pragma unroll
        for (int r = 0; r < 4; ++r) o[r] = f2bf(acc[m][r] * rn);
        *reinterpret_cast<short4v*>(P + (size_t)myrow * 128 + m * 16 + g * 4) = o;
    }
}

// ---------------------------------------------------------------------------
// Kernel 2: out[b][c] = sum_q max_k(valid) Q[b,q,:] . D[c,k,:]
// Block = (c, group of 32 b). D_c staged in LDS once; 4 waves x 8 b each,
// no barriers in the b-loop. MFMA: A=Q (M=q), B=D_c rows (N=token), K=dim.
// ---------------------------------------------------------------------------
__global__ __launch_bounds__(256) void maxsim_kernel(
    const unsigned short* __restrict__ Qb, const unsigned short* __restrict__ Db,
    const int* __restrict__ dmask, float* __restrict__ out)
{
    __shared__ __align__(16) short Dlds[256][136];  // 128 + 8 pad -> 2-way conflicts only

    const int tid = threadIdx.x;
    const int wave = tid >> 6, lane = tid & 63;
    const int l = lane & 15, g = lane >> 4;
    const int c = blockIdx.x & 127;
    const int bg = blockIdx.x >> 7;

    // --- stage D_c (256 tokens x 128 dims bf16 = 64KB), coalesced ---
    {
        const short8* src = reinterpret_cast<const short8*>(Db + (size_t)c * 256 * 128);
        #pragma unroll
        for (int i = 0; i < 16; ++i) {
            int idx = i * 256 + tid;            // 16B-chunk index
            short8 v = src[idx];
            int row = idx >> 4, col = idx & 15;
            *reinterpret_cast<short8*>(&Dlds[row][col * 8]) = v;
        }
    }
    // --- per-lane validity bits: token t = n*16 + l, n=0..15 ---
    unsigned vmask = 0;
    {
        const int* dm = dmask + c * 256;
        #pragma unroll
        for (int n = 0; n < 16; ++n) vmask |= (dm[n * 16 + l] != 0 ? 1u : 0u) << n;
    }
    __syncthreads();

    for (int ib = 0; ib < 8; ++ib) {
        const int b = bg * 32 + wave * 8 + ib;

        // A fragments: Q[b, m*16+l, ks*32 + g*8 + 0..7], L2-resident
        short8 a[2][4];
        const unsigned short* qp = Qb + (size_t)b * 32 * 128;
        #pragma unroll
        for (int m = 0; m < 2; ++m)
            #pragma unroll
            for (int ks = 0; ks < 4; ++ks)
                a[m][ks] = *reinterpret_cast<const short8*>(qp + (m * 16 + l) * 128 + ks * 32 + g * 8);

        float best[2][4];
        #pragma unroll
        for (int m = 0; m < 2; ++m)
            #pragma unroll
            for (int r = 0; r < 4; ++r) best[m][r] = -1e30f;

        // two halves of 8 token-tiles each (keeps acc at 64 VGPRs)
        #pragma unroll
        for (int half = 0; half < 2; ++half) {
            f32x4 acc[2][8];
            #pragma unroll
            for (int m = 0; m < 2; ++m)
                #pragma unroll
                for (int n = 0; n < 8; ++n) acc[m][n] = (f32x4)(0.f);

            #pragma unroll
            for (int ks = 0; ks < 4; ++ks) {
                #pragma unroll
                for (int n = 0; n < 8; ++n) {
                    const int t = (half * 8 + n) * 16 + l;
                    short8 bf = *reinterpret_cast<const short8*>(&Dlds[t][ks * 32 + g * 8]);
                    acc[0][n] = MFMA16(a[0][ks], bf, acc[0][n]);
                    acc[1][n] = MFMA16(a[1][ks], bf, acc[1][n]);
                }
            }
            // masked max over this half's token tiles (in-lane)
            #pragma unroll
            for (int n = 0; n < 8; ++n) {
                const bool valid = (vmask >> (half * 8 + n)) & 1;
                #pragma unroll
                for (int m = 0; m < 2; ++m)
                    #pragma unroll
                    for (int r = 0; r < 4; ++r) {
                        float s = valid ? acc[m][n][r] : -1e30f;
                        best[m][r] = fmaxf(best[m][r], s);
                    }
            }
        }

        // max over the 16 lanes of the group (tokens t = n*16 + l), then sum over q
        float sum = 0.f;
        #pragma unroll
        for (int m = 0; m < 2; ++m)
            #pragma unroll
            for (int r = 0; r < 4; ++r) {
                float v = best[m][r];
                v = fmaxf(v, __shfl_xor(v, 1));
                v = fmaxf(v, __shfl_xor(v, 2));
                v = fmaxf(v, __shfl_xor(v, 4));
                v = fmaxf(v, __shfl_xor(v, 8));
                sum += v;   // q = m*16 + g*4 + r
            }
        sum += __shfl_xor(sum, 16);  // sum over lane groups (q coverage 0..31)
        sum += __shfl_xor(sum, 32);
        if (lane == 0) out[b * 128 + c] = sum;
    }
}

extern "C" void kernel_launch(void* const* d_in, const int* in_sizes, int n_in,
                              void* d_out, int out_size, void* d_ws, size_t ws_size,
                              hipStream_t stream)
{
    const float* qh    = (const float*)d_in[0];   // [128,32,768]
    const float* dh    = (const float*)d_in[1];   // [128,256,768]
    const float* W     = (const float*)d_in[2];   // [128,768]
    const int*   dmask = (const int*)d_in[3];     // [128,256]
    float* out = (float*)d_out;                   // [128,128]

    unsigned short* Qb = (unsigned short*)d_ws;        // 4096 x 128 bf16 (1 MB)
    unsigned short* Db = Qb + 4096 * 128;              // 32768 x 128 bf16 (8 MB)

    // 36864 rows / 64 rows-per-block = 576 blocks
    hipLaunchKernelGGL(proj_norm_kernel, dim3(576), dim3(256), 0, stream,
                       qh, dh, W, dmask, Qb, Db);
    // 128 docs x 4 b-groups = 512 blocks
    hipLaunchKernelGGL(maxsim_kernel, dim3(512), dim3(256), 0, stream,
                       Qb, Db, dmask, out);
}